// Round 10
// baseline (290.020 us; speedup 1.0000x reference)
//
#include <hip/hip_runtime.h>
#include <hip/hip_bf16.h>
#include <cstdint>
#include <cstddef>

#define HIDN   512
#define NHEADS 8
#define BATCH  8
#define SLEN   4096
#define TLEN   512
#define SSPLIT 4
#define SCHUNK (SLEN / SSPLIT)          // 1024 s per block
#define SCL2   0.18033688f              // 0.125 * log2(e)

typedef __attribute__((ext_vector_type(8))) short   bf16x8;
typedef __attribute__((ext_vector_type(4))) float   f32x4;
typedef unsigned short u16;
typedef unsigned int   u32;

__device__ __forceinline__ u32 pkbf(float a, float b) {        // accurate RNE
    __hip_bfloat162 h = __float22bfloat162_rn(float2{a, b});
    union { __hip_bfloat162 h; u32 u; } un; un.h = h; return un.u;   // a low
}
// single-instruction pack: v_cvt_pk_bf16_f32 (a -> low16, b -> high16)
__device__ __forceinline__ u32 cvtpk(float a, float b) {
    u32 r;
    asm("v_cvt_pk_bf16_f32 %0, %1, %2" : "=v"(r) : "v"(a), "v"(b));
    return r;
}
// raw v_exp_f32 (2^x): OCML's precise exp2f is ~8-10 instr; this is 1.
__device__ __forceinline__ float fexp2(float x) {
    return __builtin_amdgcn_exp2f(x);
}
__device__ __forceinline__ void gload_lds16(const u16* g, u16* l) {
    __builtin_amdgcn_global_load_lds(
        (const __attribute__((address_space(1))) u32*)g,
        (__attribute__((address_space(3))) u32*)l, 16, 0, 0);
}

// ---------------------------------------------------------------------------
// v10: cvt shrunk to WEIGHTS + mask only (X and T are now consumed fp32
// directly by the fused projection kernel -> saves the 64MB X read + 32MB Xc
// write + 8MB T read + 4MB Tc write and one launch boundary).
// i4-unit ranges: W 262144 | mask 8192 = 270336  -> 1056 blocks.
// ---------------------------------------------------------------------------
__global__ __launch_bounds__(256) void cvt_all(
    const float* __restrict__ Wq, const float* __restrict__ Wk,
    const float* __restrict__ Wv, const float* __restrict__ Wo,
    const int* __restrict__ mask,
    u16* __restrict__ Wc, float* __restrict__ negf)
{
    int i4 = blockIdx.x * 256 + threadIdx.x;
    if (i4 >= 262144) {
        int off = i4 - 262144;
        if (off >= 8192) return;
        int4 mv = ((const int4*)mask)[off];
        float4 nv;
        nv.x = mv.x ? 0.f : -1e30f; nv.y = mv.y ? 0.f : -1e30f;
        nv.z = mv.z ? 0.f : -1e30f; nv.w = mv.w ? 0.f : -1e30f;
        ((float4*)negf)[off] = nv;
        return;
    }
    int widx = i4 >> 16;
    const float* s = (widx == 0) ? Wq : (widx == 1) ? Wk : (widx == 2) ? Wv : Wo;
    u16* d = Wc + widx * 262144;
    long off = i4 & 65535;
    float4 v = *(const float4*)(s + off * 4);
    uint2 o; o.x = pkbf(v.x, v.y); o.y = pkbf(v.z, v.w);
    *(uint2*)(d + off * 4) = o;
}

// ---------------------------------------------------------------------------
// Mixed-precision GEMM inner loop (v10): one side bf16 (weights, staged via
// global_load_lds), one side fp32 (X or T, staged global->reg->pkbf->ds_write,
// T14 early-issue: loads for tile c+1 issued before compute(c), vmcnt(6)
// waits only tile c).  Double-buffered LDS (32KB).  Conversion uses the SAME
// pkbf RNE as the old cvt pass -> bit-identical numerics.
//   F32_IS_A = false: As<-bf16 rows m0, Bs<-f32 rows n0  (K/Q projections)
//   F32_IS_A = true : As<-f32 rows m0, Bs<-bf16 rows n0  (V projection)
// ---------------------------------------------------------------------------
template<bool F32_IS_A>
__device__ __forceinline__ void mix_gemm(
    const u16* __restrict__ bp, const float* __restrict__ fp,
    int brow0, int frow0, u16 (*As)[4096], u16 (*Bs)[4096],
    f32x4 (&acc)[4][4])
{
    const int tid = threadIdx.x;
    const int lane = tid & 63, w = tid >> 6;
    const int m = lane & 15, qd = lane >> 4;
    const int wm = w >> 1, wn = w & 1;
    // bf16-side staging decomposition (2 x gload_lds16 per thread)
    const int b0r = tid >> 2,         b0c = (tid & 3) * 8,  b0d = (tid & ~63) * 8;
    const int b1r = (tid + 256) >> 2, b1d = ((tid + 256) & ~63) * 8;
    // f32-side staging decomposition (4 x float4 per thread)
    const int fr = tid >> 3, fq = tid & 7;
    u16 (*BD)[4096] = F32_IS_A ? Bs : As;   // bf16 dest
    u16 (*FD)[4096] = F32_IS_A ? As : Bs;   // f32->bf16 dest
    float4 RA[4], RB[4];

#define MISSUE(k0, bb, R) do {                                               \
        gload_lds16(bp + (size_t)(brow0 + b0r) * HIDN + (k0) + b0c,          \
                    &BD[bb][0] + b0d);                                       \
        gload_lds16(bp + (size_t)(brow0 + b1r) * HIDN + (k0) + b0c,          \
                    &BD[bb][0] + b1d);                                       \
        _Pragma("unroll")                                                    \
        for (int j = 0; j < 4; ++j)                                          \
            R[j] = *(const float4*)(fp +                                     \
                    (size_t)(frow0 + fr + 32 * j) * HIDN + (k0) + 4 * fq);   \
    } while (0)

#define MWRITE(bb, R) do {                                                   \
        _Pragma("unroll")                                                    \
        for (int j = 0; j < 4; ++j) {                                        \
            uint2 o; o.x = pkbf(R[j].x, R[j].y); o.y = pkbf(R[j].z, R[j].w); \
            *(uint2*)&FD[bb][(fr + 32 * j) * 32 + fq * 4] = o;               \
        }                                                                    \
    } while (0)

#define MCOMP(bb) do {                                                       \
        bf16x8 af[4], bf[4];                                                 \
        _Pragma("unroll")                                                    \
        for (int t = 0; t < 4; ++t) {                                        \
            af[t] = *(bf16x8*)&As[bb][(64 * wm + 16 * t + m) * 32 + 8 * qd]; \
            bf[t] = *(bf16x8*)&Bs[bb][(64 * wn + 16 * t + m) * 32 + 8 * qd]; \
        }                                                                    \
        _Pragma("unroll")                                                    \
        for (int ti2 = 0; ti2 < 4; ++ti2)                                    \
            _Pragma("unroll")                                                \
            for (int tj = 0; tj < 4; ++tj)                                   \
                acc[ti2][tj] = __builtin_amdgcn_mfma_f32_16x16x32_bf16(      \
                    af[ti2], bf[tj], acc[ti2][tj], 0, 0, 0);                 \
    } while (0)

#define MSTEP(c, bb, RCUR, RNXT, LAST) do {                                  \
        if (!(LAST)) MISSUE(((c) + 1) * 32, (bb) ^ 1, RNXT);                 \
        if (LAST) asm volatile("s_waitcnt vmcnt(0)" ::: "memory");           \
        else      asm volatile("s_waitcnt vmcnt(6)" ::: "memory");           \
        MWRITE(bb, RCUR);                                                    \
        asm volatile("s_waitcnt lgkmcnt(0)" ::: "memory");                   \
        __builtin_amdgcn_s_barrier();                                        \
        __builtin_amdgcn_sched_barrier(0);                                   \
        MCOMP(bb);                                                           \
        __builtin_amdgcn_s_barrier();                                        \
        __builtin_amdgcn_sched_barrier(0);                                   \
    } while (0)

    MISSUE(0, 0, RA);
#pragma unroll 1
    for (int cc = 0; cc < 7; ++cc) {
        MSTEP(2 * cc,     0, RA, RB, 0);
        MSTEP(2 * cc + 1, 1, RB, RA, 0);
    }
    MSTEP(14, 0, RA, RB, 0);
    MSTEP(15, 1, RB, RA, 1);

#undef MISSUE
#undef MWRITE
#undef MCOMP
#undef MSTEP
}

// W-orientation body (K and Q projections): C[o][sample] = W·X^T + bias ->
// coalesced uint2 bf16 stores into (B,H,seq,64).  A=W bf16 (m0 o-rows),
// B=X/T fp32 (n0 sample-rows).
template<int SEQ>
__device__ __forceinline__ void mixK_body(
    const u16* __restrict__ Wm, const float* __restrict__ Xf,
    const float* __restrict__ bias, u16* __restrict__ Y,
    int m0, int n0, u16 (*As)[4096], u16 (*Bs)[4096])
{
    const int tid = threadIdx.x;
    const int lane = tid & 63, w = tid >> 6;
    const int m = lane & 15, qd = lane >> 4;
    const int wm = w >> 1, wn = w & 1;

    f32x4 acc[4][4];
#pragma unroll
    for (int i = 0; i < 4; ++i)
#pragma unroll
        for (int j = 0; j < 4; ++j) acc[i][j] = (f32x4){0.f, 0.f, 0.f, 0.f};

    mix_gemm<false>(Wm, Xf, m0, n0, As, Bs, acc);

#pragma unroll
    for (int ti = 0; ti < 4; ++ti) {
        const int o = m0 + 64 * wm + 16 * ti + 4 * qd;      // 4-aligned
        const float4 bv = *(const float4*)&bias[o];
        const int h = o >> 6, d0 = o & 63;
#pragma unroll
        for (int tj = 0; tj < 4; ++tj) {
            const int n = n0 + 64 * wn + 16 * tj + m;       // sample
            const int b = n / SEQ, r = n & (SEQ - 1);
            uint2 pk;
            pk.x = pkbf(acc[ti][tj][0] + bv.x, acc[ti][tj][1] + bv.y);
            pk.y = pkbf(acc[ti][tj][2] + bv.z, acc[ti][tj][3] + bv.w);
            *(uint2*)&Y[(((size_t)(b * 8 + h)) * SEQ + r) * 64 + d0] = pk;
        }
    }
}

// A-orientation body (V projection): V^T bf16 (B,H,dk,seq) stores.
// A=X fp32 (m0 sample-rows), B=Wv bf16 (n0 o-rows).
__device__ __forceinline__ void mixV_body(
    const float* __restrict__ Xf, const u16* __restrict__ Bw,
    const float* __restrict__ bias, u16* __restrict__ Y,
    int m0, int n0, u16 (*As)[4096], u16 (*Bs)[4096])
{
    const int tid = threadIdx.x;
    const int lane = tid & 63, w = tid >> 6;
    const int m = lane & 15, qd = lane >> 4;
    const int wm = w >> 1, wn = w & 1;

    f32x4 acc[4][4];
#pragma unroll
    for (int i = 0; i < 4; ++i)
#pragma unroll
        for (int j = 0; j < 4; ++j) acc[i][j] = (f32x4){0.f, 0.f, 0.f, 0.f};

    mix_gemm<true>(Bw, Xf, n0, m0, As, Bs, acc);

#pragma unroll
    for (int ti = 0; ti < 4; ++ti) {
        const int gr0 = m0 + 64 * wm + 16 * ti + 4 * qd;
#pragma unroll
        for (int tj = 0; tj < 4; ++tj) {
            const int gcol = n0 + 64 * wn + 16 * tj + m;
            const float bv = bias[gcol];
            const int b = gr0 / SLEN, h = gcol >> 6, d = gcol & 63;
            const int r = gr0 & (SLEN - 1);
            uint2 o;
            o.x = pkbf(acc[ti][tj][0] + bv, acc[ti][tj][1] + bv);
            o.y = pkbf(acc[ti][tj][2] + bv, acc[ti][tj][3] + bv);
            *(uint2*)&Y[(((size_t)(b * 8 + h)) * 64 + d) * SLEN + r] = o;
        }
    }
}

// ---------------------------------------------------------------------------
// Fused projections: K + V + Q in ONE launch, consuming fp32 X/T directly.
//   blocks [0,1024): K-proj | [1024,2048): V-proj | [2048,2176): Q-proj
// ---------------------------------------------------------------------------
__global__ __launch_bounds__(256)
void proj_all(const u16* __restrict__ Wc,
              const float* __restrict__ Xf, const float* __restrict__ Tf,
              const float* __restrict__ bq, const float* __restrict__ bk,
              const float* __restrict__ bv,
              u16* __restrict__ Qws, u16* __restrict__ Kws,
              u16* __restrict__ Vtws)
{
    __shared__ u16 As[2][4096];
    __shared__ u16 Bs[2][4096];
    const int bid = blockIdx.x;
    if (bid < 1024) {
        mixK_body<SLEN>(Wc + 262144, Xf, bk, Kws,
                        (bid >> 8) * 128, (bid & 255) * 128, As, Bs);
    } else if (bid < 2048) {
        const int b2 = bid - 1024;
        mixV_body(Xf, Wc + 524288, bv, Vtws,
                  (b2 >> 2) * 128, (b2 & 3) * 128, As, Bs);
    } else {
        const int b2 = bid - 2048;
        mixK_body<TLEN>(Wc, Tf, bq, Qws,
                        (b2 >> 5) * 128, (b2 & 31) * 128, As, Bs);
    }
}

// ---------------------------------------------------------------------------
// Out-projection: ctx bf16 @ Wo^T + bo (fp32 out).  Simple R5-form body
// (all pipeline variants measured equal; keep the simplest).
// ---------------------------------------------------------------------------
__global__ __launch_bounds__(256)
void gemm_out(const u16* __restrict__ A, const u16* __restrict__ Bw,
              const float* __restrict__ bias, float* __restrict__ Y)
{
    __shared__ u16 As[128 * 32];
    __shared__ u16 Bs[128 * 32];
    const int tid = threadIdx.x;
    const int lane = tid & 63, w = tid >> 6;
    const int m = lane & 15, qd = lane >> 4;
    const int wm = w >> 1, wn = w & 1;
    const int m0 = blockIdx.y * 128, n0 = blockIdx.x * 128;

    f32x4 acc[4][4];
#pragma unroll
    for (int i = 0; i < 4; ++i)
#pragma unroll
        for (int j = 0; j < 4; ++j) acc[i][j] = (f32x4){0.f, 0.f, 0.f, 0.f};

    for (int k0 = 0; k0 < HIDN; k0 += 32) {
#pragma unroll
        for (int r = 0; r < 2; ++r) {
            const int f = tid + r * 256;
            const int row = f >> 2, c8 = (f & 3) * 8;
            const int fb = f & ~63;
            gload_lds16(A  + (size_t)(m0 + row) * HIDN + k0 + c8, As + fb * 8);
            gload_lds16(Bw + (size_t)(n0 + row) * HIDN + k0 + c8, Bs + fb * 8);
        }
        __syncthreads();
        bf16x8 af[4], bf[4];
#pragma unroll
        for (int t = 0; t < 4; ++t) {
            af[t] = *(bf16x8*)&As[(64 * wm + 16 * t + m) * 32 + 8 * qd];
            bf[t] = *(bf16x8*)&Bs[(64 * wn + 16 * t + m) * 32 + 8 * qd];
        }
#pragma unroll
        for (int ti = 0; ti < 4; ++ti)
#pragma unroll
            for (int tj = 0; tj < 4; ++tj)
                acc[ti][tj] = __builtin_amdgcn_mfma_f32_16x16x32_bf16(
                    af[ti], bf[tj], acc[ti][tj], 0, 0, 0);
        __syncthreads();
    }

#pragma unroll
    for (int ti = 0; ti < 4; ++ti) {
        const int gr0 = m0 + 64 * wm + 16 * ti + 4 * qd;
#pragma unroll
        for (int tj = 0; tj < 4; ++tj) {
            const int gcol = n0 + 64 * wn + 16 * tj + m;
            const float bv = bias[gcol];
#pragma unroll
            for (int i = 0; i < 4; ++i)
                Y[(size_t)(gr0 + i) * HIDN + gcol] = acc[ti][tj][i] + bv;
        }
    }
}

// ---------------------------------------------------------------------------
// Flash attention v5 (unchanged): cooperative LDS staging + counted-vmcnt
// pipeline + raw v_exp_f32.
// Grid (ti=2, si=4, bh=64), 256 thr / 4 waves; wave owns 64 t (4 strips).
// P relayout C->B via per-wave LDS round-trip (XOR-swizzled, no barriers).
// ---------------------------------------------------------------------------
__global__ __launch_bounds__(256, 2)
void attn_part(const u16* __restrict__ Q, const u16* __restrict__ K,
               const u16* __restrict__ Vt, const float* __restrict__ negf,
               float* __restrict__ Opart, float* __restrict__ lpart)
{
    __shared__ char Psh[32768];       // 4 waves x 4 ts x 2KB
    __shared__ u16  KVl[2][8192];     // [buf][ K 4096 u16 | V 4096 u16 ]
    __shared__ float Ngl[1024];       // negf slice for this (b, si)
    const int tid = threadIdx.x;
    const int lane = tid & 63, w = tid >> 6;
    const int m = lane & 15, qd = lane >> 4;
    const int ti = blockIdx.x, si = blockIdx.y, bh = blockIdx.z;
    const int b = bh >> 3;

    const u16* Qp = Q + ((size_t)bh * TLEN + ti * 256) * 64;
    const u16* Kp = K + (size_t)bh * SLEN * 64;
    const u16* Vp = Vt + (size_t)bh * 64 * SLEN;
    const float* np = negf + (size_t)b * SLEN;
    const int s_beg = si * SCHUNK;

    // --- staging decomposition: thread -> (row, swizzled 16B granule) ---
    const int sr = tid >> 3;                      // row 0..31 (half-tile)
    const int sg = ((tid & 7) ^ (sr & 7)) * 8;    // swizzled granule, elems
    const u16* kgb = Kp + (size_t)s_beg * 64 + sr * 64 + sg;
    const u16* vgb = Vp + s_beg + (size_t)sr * SLEN + sg;
    u16* kd = &KVl[0][0]    + tid * 8;
    u16* vd = &KVl[0][4096] + tid * 8;

#define STAGE(cc, bb) do {                                                   \
        const u16* kg_ = kgb + (size_t)(cc) * 4096;                          \
        const u16* vg_ = vgb + (cc) * 64;                                    \
        u16* kd_ = kd + (bb) * 8192;                                         \
        u16* vd_ = vd + (bb) * 8192;                                         \
        gload_lds16(kg_,                     kd_);                           \
        gload_lds16(kg_ + 32 * 64,           kd_ + 2048);                    \
        gload_lds16(vg_,                     vd_);                           \
        gload_lds16(vg_ + (size_t)32 * SLEN, vd_ + 2048);                    \
    } while (0)

    // LDS addresses: row t=m (128B), 8B units XOR-swizzled by m -> conflict-free
    const int wb = w * 8192 + m * 128;
    int waddr[4], ra0[2], ra1[2];
#pragma unroll
    for (int st = 0; st < 4; ++st) waddr[st] = wb + (((4 * st + qd) ^ m) << 3);
#pragma unroll
    for (int ks = 0; ks < 2; ++ks) {
        const int u0 = 8 * ks + 2 * qd;
        ra0[ks] = wb + (((u0) ^ m) << 3);
        ra1[ks] = wb + (((u0 + 1) ^ m) << 3);
    }
    // frag-read swizzled column offsets (u16 units) within K/V LDS tiles
    const int x0 = ((qd    ) ^ (m & 7)) * 8;      // kh/ks = 0
    const int x1 = ((4 + qd) ^ (m & 7)) * 8;      // kh/ks = 1

    bf16x8 qf[4][2];
#pragma unroll
    for (int ts = 0; ts < 4; ++ts)
#pragma unroll
        for (int kh = 0; kh < 2; ++kh)
            qf[ts][kh] = *(const bf16x8*)(Qp + (64 * w + 16 * ts + m) * 64 +
                                          32 * kh + 8 * qd);

    f32x4 O[4][4];
#pragma unroll
    for (int ts = 0; ts < 4; ++ts)
#pragma unroll
        for (int dt = 0; dt < 4; ++dt) O[ts][dt] = (f32x4){0.f, 0.f, 0.f, 0.f};
    float lr[4] = {0.f, 0.f, 0.f, 0.f};

#define CHUNK(cc) do {                                                       \
        const u16* Kl = &KVl[(cc) & 1][0];                                   \
        const u16* Vl = &KVl[(cc) & 1][4096];                                \
        bf16x8 kf[4][2];                                                     \
        _Pragma("unroll")                                                    \
        for (int st = 0; st < 4; ++st) {                                     \
            kf[st][0] = *(const bf16x8*)&Kl[st * 1024 + m * 64 + x0];        \
            kf[st][1] = *(const bf16x8*)&Kl[st * 1024 + m * 64 + x1];        \
        }                                                                    \
        float4 ng[4];                                                        \
        _Pragma("unroll")                                                    \
        for (int st = 0; st < 4; ++st)                                       \
            ng[st] = *(const float4*)&Ngl[((cc) << 6) + (st << 4) + (qd << 2)]; \
        _Pragma("unroll")                                                    \
        for (int ts = 0; ts < 4; ++ts) {                                     \
            f32x4 S[4];                                                      \
            _Pragma("unroll")                                                \
            for (int st = 0; st < 4; ++st) {                                 \
                f32x4 cc2 = (f32x4){0.f, 0.f, 0.f, 0.f};                     \
                cc2 = __builtin_amdgcn_mfma_f32_16x16x32_bf16(               \
                          kf[st][0], qf[ts][0], cc2, 0, 0, 0);               \
                cc2 = __builtin_amdgcn_mfma_f32_16x16x32_bf16(               \
                          kf[st][1], qf[ts][1], cc2, 0, 0, 0);               \
                S[st] = cc2;                                                 \
            }                                                                \
            float ls = 0.f;                                                  \
            _Pragma("unroll")                                                \
            for (int st = 0; st < 4; ++st) {                                 \
                const float p0 = fexp2(fmaf(S[st][0], SCL2, ng[st].x));      \
                const float p1 = fexp2(fmaf(S[st][1], SCL2, ng[st].y));      \
                const float p2 = fexp2(fmaf(S[st][2], SCL2, ng[st].z));      \
                const float p3 = fexp2(fmaf(S[st][3], SCL2, ng[st].w));      \
                ls += (p0 + p1) + (p2 + p3);                                 \
                *(uint2*)&Psh[waddr[st] + ts * 2048] =                       \
                    make_uint2(cvtpk(p0, p1), cvtpk(p2, p3));                \
            }                                                                \
            lr[ts] += ls;                                                    \
        }                                                                    \
        bf16x8 vf[4][2];                                                     \
        _Pragma("unroll")                                                    \
        for (int dt = 0; dt < 4; ++dt) {                                     \
            vf[dt][0] = *(const bf16x8*)&Vl[dt * 1024 + m * 64 + x0];        \
            vf[dt][1] = *(const bf16x8*)&Vl[dt * 1024 + m * 64 + x1];        \
        }                                                                    \
        __builtin_amdgcn_s_setprio(1);                                       \
        _Pragma("unroll")                                                    \
        for (int ts = 0; ts < 4; ++ts) {                                     \
            _Pragma("unroll")                                                \
            for (int ks = 0; ks < 2; ++ks) {                                 \
                const uint2 r0 = *(uint2*)&Psh[ra0[ks] + ts * 2048];         \
                const uint2 r1 = *(uint2*)&Psh[ra1[ks] + ts * 2048];         \
                union { uint4 u; bf16x8 v; } bu;                             \
                bu.u = make_uint4(r0.x, r0.y, r1.x, r1.y);                   \
                O[ts][0] = __builtin_amdgcn_mfma_f32_16x16x32_bf16(          \
                               vf[0][ks], bu.v, O[ts][0], 0, 0, 0);          \
                O[ts][1] = __builtin_amdgcn_mfma_f32_16x16x32_bf16(          \
                               vf[1][ks], bu.v, O[ts][1], 0, 0, 0);          \
                O[ts][2] = __builtin_amdgcn_mfma_f32_16x16x32_bf16(          \
                               vf[2][ks], bu.v, O[ts][2], 0, 0, 0);          \
                O[ts][3] = __builtin_amdgcn_mfma_f32_16x16x32_bf16(          \
                               vf[3][ks], bu.v, O[ts][3], 0, 0, 0);          \
            }                                                                \
        }                                                                    \
        __builtin_amdgcn_s_setprio(0);                                       \
    } while (0)

    // --- pipeline: stage(c+1) in flight across compute(c) ---
    STAGE(0, 0);
    gload_lds16((const u16*)(np + s_beg) + (size_t)tid * 8,
                ((u16*)Ngl) + tid * 8);
#pragma unroll 1
    for (int c = 0; c < (SCHUNK / 64) - 1; ++c) {
        STAGE(c + 1, (c + 1) & 1);
        asm volatile("s_waitcnt vmcnt(4)" ::: "memory");
        __builtin_amdgcn_s_barrier();
        __builtin_amdgcn_sched_barrier(0);
        CHUNK(c);
        __builtin_amdgcn_s_barrier();
        __builtin_amdgcn_sched_barrier(0);
    }
    asm volatile("s_waitcnt vmcnt(0)" ::: "memory");
    __builtin_amdgcn_s_barrier();
    __builtin_amdgcn_sched_barrier(0);
    CHUNK((SCHUNK / 64) - 1);

#undef STAGE
#undef CHUNK

#pragma unroll
    for (int ts = 0; ts < 4; ++ts) {
        float l = lr[ts];
        l += __shfl_xor(l, 16, 64);
        l += __shfl_xor(l, 32, 64);
        const int t = ti * 256 + 64 * w + 16 * ts + m;
        float* Ob = Opart + (((size_t)(si * 64 + bh)) * 512 + t) * 64;
#pragma unroll
        for (int dt = 0; dt < 4; ++dt)
            *(f32x4*)&Ob[16 * dt + 4 * qd] = O[ts][dt];
        if (qd == 0)
            lpart[((size_t)(si * 64 + bh)) * 512 + t] = l;
    }
}

// ---------------------------------------------------------------------------
// Combine split-S partials: ctx(B,T,512) bf16 = (sum O)/(sum l).
// ---------------------------------------------------------------------------
__global__ __launch_bounds__(256)
void attn_combine(const float* __restrict__ Opart, const float* __restrict__ lpart,
                  u16* __restrict__ ctx)
{
    const int gid = blockIdx.x * 256 + threadIdx.x;
    const int d4 = gid & 15, t = (gid >> 4) & 511, bh = gid >> 13;
    const int b = bh >> 3, h = bh & 7;
    float4 o = {0.f, 0.f, 0.f, 0.f}; float l = 0.f;
#pragma unroll
    for (int si = 0; si < SSPLIT; ++si) {
        const size_t base = ((size_t)(si * 64 + bh)) * 512 + t;
        l += lpart[base];
        const float4 v = *(const float4*)(Opart + base * 64 + d4 * 4);
        o.x += v.x; o.y += v.y; o.z += v.z; o.w += v.w;
    }
    const float r = 1.f / l;
    uint2 pk; pk.x = pkbf(o.x * r, o.y * r); pk.y = pkbf(o.z * r, o.w * r);
    *(uint2*)&ctx[((size_t)(b * 512 + t)) * 512 + h * 64 + d4 * 4] = pk;
}

// ---------------------------------------------------------------------------
extern "C" void kernel_launch(void* const* d_in, const int* in_sizes, int n_in,
                              void* d_out, int out_size, void* d_ws, size_t ws_size,
                              hipStream_t stream)
{
    const float* inputs  = (const float*)d_in[0];
    const float* targets = (const float*)d_in[1];
    const int*   mask    = (const int*)d_in[2];
    const float* Wq = (const float*)d_in[3];
    const float* bq = (const float*)d_in[4];
    const float* Wk = (const float*)d_in[5];
    const float* bk = (const float*)d_in[6];
    const float* Wv = (const float*)d_in[7];
    const float* bv = (const float*)d_in[8];
    const float* Wo = (const float*)d_in[9];
    const float* bo = (const float*)d_in[10];

    char* ws = (char*)d_ws;
    u16*   Wc    = (u16*)(ws + 37748736);                 //  2,097,152
    float* negf  = (float*)(ws + 39845888);               //    131,072
    u16*   Qws   = (u16*)(ws + 39976960);                 //  4,194,304
    u16*   Kws   = (u16*)(ws + 44171264);                 // 33,554,432
    u16*   Vtws  = (u16*)(ws + 77725696);                 // 33,554,432
    u16*   Cws   = (u16*)(ws + 111280128);                //  4,194,304
    float* Opart = (float*)(ws + 115474432);              // 33,554,432
    float* lpart = (float*)(ws + 149028864);              //    524,288

    cvt_all<<<1056, 256, 0, stream>>>(Wq, Wk, Wv, Wo, mask, Wc, negf);

    // Fused Q+K+V projections, consuming fp32 inputs/targets directly
    proj_all<<<2176, 256, 0, stream>>>(Wc, inputs, targets, bq, bk, bv,
                                       Qws, Kws, Vtws);

    attn_part<<<dim3(2, SSPLIT, 64), 256, 0, stream>>>(Qws, Kws, Vtws, negf,
                                                       Opart, lpart);
    attn_combine<<<2048, 256, 0, stream>>>(Opart, lpart, Cws);

    gemm_out<<<dim3(4, 32), 256, 0, stream>>>(Cws, Wc + 786432, bo,
                                              (float*)d_out);
}